// Round 1
// baseline (142.526 us; speedup 1.0000x reference)
//
#include <hip/hip_runtime.h>
#include <cstdint>
#include <cstddef>

typedef __bf16 bf16x8 __attribute__((ext_vector_type(8)));
typedef float f32x4 __attribute__((ext_vector_type(4)));
typedef unsigned short u16x8 __attribute__((ext_vector_type(8)));

#define MFMA16(a, b, c) __builtin_amdgcn_mfma_f32_16x16x32_bf16(a, b, c, 0, 0, 0)

static __device__ __forceinline__ bf16x8 ld_bf16x8(const __bf16* p) {
    return *reinterpret_cast<const bf16x8*>(p);
}

// ---------------- f32 -> bf16 convert (8 elems/thread) ----------------
__global__ void cvt_kernel(const float* __restrict__ src, __bf16* __restrict__ dst, int n8) {
    int i = blockIdx.x * blockDim.x + threadIdx.x;
    if (i >= n8) return;
    const float4* s4 = reinterpret_cast<const float4*>(src) + (size_t)i * 2;
    float4 a = s4[0], b = s4[1];
    bf16x8 o;
    o[0] = (__bf16)a.x; o[1] = (__bf16)a.y; o[2] = (__bf16)a.z; o[3] = (__bf16)a.w;
    o[4] = (__bf16)b.x; o[5] = (__bf16)b.y; o[6] = (__bf16)b.z; o[7] = (__bf16)b.w;
    reinterpret_cast<bf16x8*>(dst)[i] = o;
}

// ---------------- shared GEMM mainloop: C(128x128) += A(128xK) * B(KxN tile) ----------------
// A: [M][K] bf16 row-major.  B: [K][N] bf16 row-major (staged transposed to LDS [n][k]).
__device__ __forceinline__ void gemm_mainloop(const __bf16* __restrict__ A,
                                              const __bf16* __restrict__ B,
                                              int N, int K, int row0, int col0,
                                              __bf16* Als, __bf16* Bls, f32x4 acc[4][4]) {
    const int tid = threadIdx.x;
    const int lane = tid & 63;
    const int wid = tid >> 6;
    const int wr = wid >> 1, wc = wid & 1;
    // A staging: thread -> row=tid/2, 16 cols at (tid&1)*16
    const int ar = tid >> 1, ac = (tid & 1) << 4;
    // B staging (transposed): thread -> n=tid&127, 16 k's at (tid>>7)*16
    const int bn = tid & 127, bk = (tid >> 7) << 4;

    for (int k0 = 0; k0 < K; k0 += 32) {
        const __bf16* asrc = A + (size_t)(row0 + ar) * K + k0 + ac;
        u16x8 a0 = *reinterpret_cast<const u16x8*>(asrc);
        u16x8 a1 = *reinterpret_cast<const u16x8*>(asrc + 8);

        const unsigned short* bsrc =
            reinterpret_cast<const unsigned short*>(B + (size_t)(k0 + bk) * N + col0 + bn);
        u16x8 b0, b1;
        #pragma unroll
        for (int i = 0; i < 8; i++) b0[i] = bsrc[(size_t)i * N];
        #pragma unroll
        for (int i = 0; i < 8; i++) b1[i] = bsrc[(size_t)(i + 8) * N];

        *reinterpret_cast<u16x8*>(&Als[ar * 40 + ac]) = a0;
        *reinterpret_cast<u16x8*>(&Als[ar * 40 + ac + 8]) = a1;
        *reinterpret_cast<u16x8*>(&Bls[bn * 40 + bk]) = b0;
        *reinterpret_cast<u16x8*>(&Bls[bn * 40 + bk + 8]) = b1;
        __syncthreads();

        bf16x8 af[4], bfr[4];
        #pragma unroll
        for (int m = 0; m < 4; m++)
            af[m] = ld_bf16x8(&Als[(wr * 64 + m * 16 + (lane & 15)) * 40 + ((lane >> 4) << 3)]);
        #pragma unroll
        for (int n = 0; n < 4; n++)
            bfr[n] = ld_bf16x8(&Bls[(wc * 64 + n * 16 + (lane & 15)) * 40 + ((lane >> 4) << 3)]);
        #pragma unroll
        for (int m = 0; m < 4; m++) {
            #pragma unroll
            for (int n = 0; n < 4; n++) {
                acc[m][n] = MFMA16(af[m], bfr[n], acc[m][n]);
            }
        }
        __syncthreads();
    }
}

// ---------------- QKV GEMM: x(4096x1024) @ w_attn(1024x3072) + b_attn ----------------
__global__ __launch_bounds__(256) void gemm_qkv_kernel(const __bf16* __restrict__ xb,
                                                       const __bf16* __restrict__ wab,
                                                       const float* __restrict__ bias,
                                                       __bf16* __restrict__ qb,
                                                       __bf16* __restrict__ kb,
                                                       __bf16* __restrict__ vb,
                                                       float* __restrict__ present) {
    __shared__ __bf16 Als[128 * 40];
    __shared__ __bf16 Bls[128 * 40];
    f32x4 acc[4][4] = {};
    const int row0 = blockIdx.y * 128, col0 = blockIdx.x * 128;
    gemm_mainloop(xb, wab, 3072, 1024, row0, col0, Als, Bls, acc);

    const int lane = threadIdx.x & 63, wid = threadIdx.x >> 6;
    const int wr = wid >> 1, wc = wid & 1;
    #pragma unroll
    for (int n = 0; n < 4; n++) {
        int col = col0 + wc * 64 + n * 16 + (lane & 15);
        int part = col >> 10;          // 0=q 1=k 2=v
        int hh = (col >> 6) & 15;      // head
        int dd = col & 63;             // dim within head
        float bv = bias[col];
        #pragma unroll
        for (int m = 0; m < 4; m++) {
            #pragma unroll
            for (int r = 0; r < 4; r++) {
                int row = row0 + wr * 64 + m * 16 + ((lane >> 4) << 2) + r;
                int bb = row >> 11, ss = row & 2047;
                float val = acc[m][n][r] + bv;
                size_t qi = (((size_t)(bb * 16 + hh)) * 2048 + ss) * 64 + dd;
                if (part == 0) {
                    qb[qi] = (__bf16)val;
                } else if (part == 1) {
                    kb[qi] = (__bf16)val;
                    present[(((size_t)((bb * 2 + 0) * 16 + hh)) * 2048 + ss) * 64 + dd] = val;
                } else {
                    vb[qi] = (__bf16)val;
                    present[(((size_t)((bb * 2 + 1) * 16 + hh)) * 2048 + ss) * 64 + dd] = val;
                }
            }
        }
    }
}

// ---------------- Proj GEMM: a(4096x1024) @ w_proj(1024x1024) + b_proj ----------------
__global__ __launch_bounds__(256) void gemm_proj_kernel(const __bf16* __restrict__ ab,
                                                        const __bf16* __restrict__ wpb,
                                                        const float* __restrict__ bias,
                                                        float* __restrict__ out) {
    __shared__ __bf16 Als[128 * 40];
    __shared__ __bf16 Bls[128 * 40];
    f32x4 acc[4][4] = {};
    const int row0 = blockIdx.y * 128, col0 = blockIdx.x * 128;
    gemm_mainloop(ab, wpb, 1024, 1024, row0, col0, Als, Bls, acc);

    const int lane = threadIdx.x & 63, wid = threadIdx.x >> 6;
    const int wr = wid >> 1, wc = wid & 1;
    #pragma unroll
    for (int n = 0; n < 4; n++) {
        int col = col0 + wc * 64 + n * 16 + (lane & 15);
        float bv = bias[col];
        #pragma unroll
        for (int m = 0; m < 4; m++) {
            #pragma unroll
            for (int r = 0; r < 4; r++) {
                int row = row0 + wr * 64 + m * 16 + ((lane >> 4) << 2) + r;
                out[(size_t)row * 1024 + col] = acc[m][n][r] + bv;
            }
        }
    }
}

// ---------------- sliding-window causal flash attention ----------------
// grid: (B*H) * (S/64) blocks, 256 threads (4 waves, each wave owns 16 query rows)
__global__ __launch_bounds__(256) void attn_kernel(const __bf16* __restrict__ qb,
                                                   const __bf16* __restrict__ kb,
                                                   const __bf16* __restrict__ vb,
                                                   __bf16* __restrict__ ab) {
    __shared__ __bf16 Pls[4][16 * 40];  // per-wave P tile [16 q][32 k], padded to 40
    const int bh = blockIdx.x >> 5;     // b*16 + h
    const int qt = blockIdx.x & 31;
    const int lane = threadIdx.x & 63, wid = threadIdx.x >> 6;
    const int q0w = qt * 64 + wid * 16;

    const __bf16* Qh = qb + (size_t)bh * 2048 * 64;
    const __bf16* Kh = kb + (size_t)bh * 2048 * 64;
    const __bf16* Vh = vb + (size_t)bh * 2048 * 64;
    __bf16* Pw = &Pls[wid][0];

    // load Q fragments (16 rows x 64 d) once
    bf16x8 qf[2];
    {
        int qr = q0w + (lane & 15);
        const __bf16* qp = Qh + (size_t)qr * 64 + ((lane >> 4) << 3);
        qf[0] = ld_bf16x8(qp);
        qf[1] = ld_bf16x8(qp + 32);
    }

    f32x4 o[4];
    #pragma unroll
    for (int dt = 0; dt < 4; dt++) o[dt] = (f32x4){0.f, 0.f, 0.f, 0.f};
    float mrun[4] = {-1e30f, -1e30f, -1e30f, -1e30f};
    float srun[4] = {0.f, 0.f, 0.f, 0.f};

    const float scale = 0.125f;  // 1/sqrt(64)
    int klo = q0w - 255;
    int kt0 = klo > 0 ? (klo & ~31) : 0;

    for (int kt = kt0; kt <= q0w + 15; kt += 32) {
        // ---- scores for 32 keys (two 16-key subtiles) ----
        f32x4 s[2];
        #pragma unroll
        for (int kc = 0; kc < 2; kc++) {
            int krow = kt + kc * 16 + (lane & 15);
            krow = krow < 2047 ? krow : 2047;
            const __bf16* kp = Kh + (size_t)krow * 64 + ((lane >> 4) << 3);
            bf16x8 kf0 = ld_bf16x8(kp);
            bf16x8 kf1 = ld_bf16x8(kp + 32);
            f32x4 a = (f32x4){0.f, 0.f, 0.f, 0.f};
            a = MFMA16(qf[0], kf0, a);
            a = MFMA16(qf[1], kf1, a);
            s[kc] = a;
        }
        // ---- joint online softmax over the 32 keys ----
        float p0v[4], p1v[4], factor[4];
        #pragma unroll
        for (int r = 0; r < 4; r++) {
            int q = q0w + ((lane >> 4) << 2) + r;
            int k0i = kt + (lane & 15);
            int k1i = k0i + 16;
            bool ok0 = (k0i <= q) && (k0i > q - 256);
            bool ok1 = (k1i <= q) && (k1i > q - 256);
            float s0 = ok0 ? s[0][r] * scale : -1e30f;
            float s1 = ok1 ? s[1][r] * scale : -1e30f;
            float mx = fmaxf(s0, s1);
            #pragma unroll
            for (int off = 1; off < 16; off <<= 1) mx = fmaxf(mx, __shfl_xor(mx, off));
            float mn = fmaxf(mrun[r], mx);
            float f = __expf(mrun[r] - mn);
            float p0 = ok0 ? __expf(s0 - mn) : 0.f;
            float p1 = ok1 ? __expf(s1 - mn) : 0.f;
            float ps = p0 + p1;
            #pragma unroll
            for (int off = 1; off < 16; off <<= 1) ps += __shfl_xor(ps, off);
            srun[r] = srun[r] * f + ps;
            mrun[r] = mn;
            factor[r] = f;
            p0v[r] = p0;
            p1v[r] = p1;
        }
        #pragma unroll
        for (int dt = 0; dt < 4; dt++) {
            #pragma unroll
            for (int r = 0; r < 4; r++) o[dt][r] *= factor[r];
        }
        // ---- write P (bf16) to per-wave LDS, [q][key] with pad 40 ----
        #pragma unroll
        for (int r = 0; r < 4; r++) {
            int qrow = ((lane >> 4) << 2) + r;
            Pw[qrow * 40 + (lane & 15)] = (__bf16)p0v[r];
            Pw[qrow * 40 + 16 + (lane & 15)] = (__bf16)p1v[r];
        }
        asm volatile("s_waitcnt lgkmcnt(0)" ::: "memory");
        // ---- PV: o(16x64) += P(16x32) * V(32x64) ----
        bf16x8 pf = ld_bf16x8(&Pw[(lane & 15) * 40 + ((lane >> 4) << 3)]);
        #pragma unroll
        for (int dt = 0; dt < 4; dt++) {
            u16x8 vtmp;
            #pragma unroll
            for (int j = 0; j < 8; j++) {
                int vrow = kt + ((lane >> 4) << 3) + j;
                vrow = vrow < 2047 ? vrow : 2047;
                vtmp[j] = reinterpret_cast<const unsigned short*>(Vh)[(size_t)vrow * 64 + dt * 16 + (lane & 15)];
            }
            bf16x8 vf = __builtin_bit_cast(bf16x8, vtmp);
            o[dt] = MFMA16(pf, vf, o[dt]);
        }
    }

    // ---- normalize and store to a_buf [B*S][1024] at head offset ----
    const int bb = bh >> 4, hh = bh & 15;
    #pragma unroll
    for (int r = 0; r < 4; r++) {
        int q = q0w + ((lane >> 4) << 2) + r;
        float inv = 1.f / srun[r];
        size_t base = ((size_t)bb * 2048 + q) * 1024 + hh * 64;
        #pragma unroll
        for (int dt = 0; dt < 4; dt++) {
            ab[base + dt * 16 + (lane & 15)] = (__bf16)(o[dt][r] * inv);
        }
    }
}

// ---------------- launch ----------------
extern "C" void kernel_launch(void* const* d_in, const int* in_sizes, int n_in,
                              void* d_out, int out_size, void* d_ws, size_t ws_size,
                              hipStream_t stream) {
    const float* x = (const float*)d_in[0];       // [2,2048,1024]
    const float* w_attn = (const float*)d_in[1];  // [1024,3072]
    const float* b_attn = (const float*)d_in[2];  // [3072]
    const float* w_proj = (const float*)d_in[3];  // [1024,1024]
    const float* b_proj = (const float*)d_in[4];  // [1024]

    float* out = (float*)d_out;                 // [2,2048,1024]
    float* present = out + (size_t)2 * 2048 * 1024;  // [2,2,16,2048,64]

    char* w = (char*)d_ws;
    __bf16* xb  = (__bf16*)(w);                  // 8,388,608 B (also reused as a_buf)
    __bf16* wab = (__bf16*)(w + 8388608);        // 6,291,456 B
    __bf16* wpb = (__bf16*)(w + 14680064);       // 2,097,152 B
    __bf16* qb  = (__bf16*)(w + 16777216);       // 8,388,608 B
    __bf16* kb  = (__bf16*)(w + 25165824);       // 8,388,608 B
    __bf16* vb  = (__bf16*)(w + 33554432);       // 8,388,608 B
    __bf16* ab  = xb;  // a_buf reuses xb region (x consumed before attention writes)

    // converts
    cvt_kernel<<<2048, 256, 0, stream>>>(x, xb, 524288);
    cvt_kernel<<<1536, 256, 0, stream>>>(w_attn, wab, 393216);
    cvt_kernel<<<512, 256, 0, stream>>>(w_proj, wpb, 131072);

    // QKV projection
    gemm_qkv_kernel<<<dim3(24, 32), 256, 0, stream>>>(xb, wab, b_attn, qb, kb, vb, present);

    // attention
    attn_kernel<<<1024, 256, 0, stream>>>(qb, kb, vb, ab);

    // output projection
    gemm_proj_kernel<<<dim3(8, 32), 256, 0, stream>>>(ab, wpb, b_proj, out);
}